// Round 10
// baseline (252.576 us; speedup 1.0000x reference)
//
#include <hip/hip_runtime.h>
#include <hip/hip_bf16.h>
#include <cstdint>

#define T_TOK 8192
#define H_DIM 2048
#define N_EXP 8
#define FLAGBIT 0x80000000u

typedef __attribute__((ext_vector_type(4))) float f32x4;
typedef __attribute__((ext_vector_type(8))) short bf16x8;

__device__ __forceinline__ unsigned short f2bf(float f) {
  unsigned int u = __builtin_bit_cast(unsigned int, f);
  u += 0x7fffu + ((u >> 16) & 1u);  // RNE
  return (unsigned short)(u >> 16);
}

__device__ __forceinline__ unsigned cvtpk(float lo, float hi) {
  unsigned r;
  asm("v_cvt_pk_bf16_f32 %0, %1, %2" : "=v"(r) : "v"(lo), "v"(hi));
  return r;
}
__device__ __forceinline__ uint4 pk16(const f32x4& a, const f32x4& b) {
  uint4 r;
  r.x = cvtpk(a[0], a[1]); r.y = cvtpk(a[2], a[3]);
  r.z = cvtpk(b[0], b[1]); r.w = cvtpk(b[2], b[3]);
  return r;
}

#define GLL(SRC, DST) __builtin_amdgcn_global_load_lds( \
    (const __attribute__((address_space(1))) void*)(SRC), \
    (__attribute__((address_space(3))) void*)(DST), 16, 0, 0)

// ---- router: 4 tokens/wave, atomic-free, writes idx + bf16 x ----
__global__ __launch_bounds__(256, 2) void k_router(const float* __restrict__ x,
    const float* __restrict__ wr, unsigned short* __restrict__ xb,
    int* __restrict__ idx)
{
  const int wv = threadIdx.x >> 6, lane = threadIdx.x & 63;
  const int t0 = (blockIdx.x * 4 + wv) * 4;
  float acc[4][N_EXP];
#pragma unroll
  for (int tt = 0; tt < 4; ++tt)
#pragma unroll
    for (int e = 0; e < N_EXP; ++e) acc[tt][e] = 0.f;
#pragma unroll
  for (int c = 0; c < H_DIM / 256; ++c) {
    const int h = c * 256 + lane * 4;
    float4 wvv[N_EXP];
#pragma unroll
    for (int e = 0; e < N_EXP; ++e)
      wvv[e] = *reinterpret_cast<const float4*>(wr + e * H_DIM + h);
#pragma unroll
    for (int tt = 0; tt < 4; ++tt) {
      const float4 xv = *reinterpret_cast<const float4*>(x + (size_t)(t0 + tt) * H_DIM + h);
      ushort4 bv;
      bv.x = f2bf(xv.x); bv.y = f2bf(xv.y); bv.z = f2bf(xv.z); bv.w = f2bf(xv.w);
      *reinterpret_cast<ushort4*>(xb + (size_t)(t0 + tt) * H_DIM + h) = bv;
#pragma unroll
      for (int e = 0; e < N_EXP; ++e) {
        acc[tt][e] = fmaf(xv.x, wvv[e].x, acc[tt][e]);
        acc[tt][e] = fmaf(xv.y, wvv[e].y, acc[tt][e]);
        acc[tt][e] = fmaf(xv.z, wvv[e].z, acc[tt][e]);
        acc[tt][e] = fmaf(xv.w, wvv[e].w, acc[tt][e]);
      }
    }
  }
#pragma unroll
  for (int off = 32; off >= 1; off >>= 1)
#pragma unroll
    for (int tt = 0; tt < 4; ++tt)
#pragma unroll
      for (int e = 0; e < N_EXP; ++e) acc[tt][e] += __shfl_xor(acc[tt][e], off, 64);
  if (lane == 0) {
#pragma unroll
    for (int tt = 0; tt < 4; ++tt) {
      float best = acc[tt][0]; int be = 0;
#pragma unroll
      for (int e = 1; e < N_EXP; ++e) if (acc[tt][e] > best) { best = acc[tt][e]; be = e; }
      idx[t0 + tt] = be;
    }
  }
}

// ---- fused sort: hist + scan + stable place + maps, one block of 1024 ----
__global__ __launch_bounds__(1024) void k_sort(const int* __restrict__ idx,
    int* __restrict__ tlist, int* __restrict__ estar, int* __restrict__ mlo,
    int* __restrict__ mhi, int* __restrict__ rpos, int* __restrict__ rtile,
    int* __restrict__ rtc)
{
  __shared__ int wc[N_EXP][128];
  __shared__ int wbase[N_EXP][128];
  __shared__ int sTot[N_EXP];
  __shared__ int off[N_EXP + 1];
  __shared__ int sE[32], sCnt[N_EXP], sBase[N_EXP];
  const int tid = threadIdx.x, w = tid >> 6, l = tid & 63;
  int myE[8];
#pragma unroll
  for (int j = 0; j < 8; ++j) {
    myE[j] = idx[j * 1024 + tid];
#pragma unroll
    for (int e = 0; e < N_EXP; ++e) {
      const unsigned long long bm = __ballot(myE[j] == e);
      if (l == e) wc[e][j * 16 + w] = __popcll(bm);
    }
  }
  __syncthreads();
  if (tid < N_EXP) {
    int s = 0;
    for (int k = 0; k < 128; ++k) { wbase[tid][k] = s; s += wc[tid][k]; }
    sTot[tid] = s;
  }
  __syncthreads();
  if (tid == 0) {
    off[0] = 0;
    for (int e = 0; e < N_EXP; ++e) off[e + 1] = off[e] + sTot[e];
  }
  __syncthreads();
#pragma unroll
  for (int j = 0; j < 8; ++j) {
    int rank = 0;
#pragma unroll
    for (int e = 0; e < N_EXP; ++e) {
      const unsigned long long bm = __ballot(myE[j] == e);
      if (myE[j] == e) rank = __popcll(bm & ((1ull << l) - 1ull));
    }
    tlist[off[myE[j]] + wbase[myE[j]][j * 16 + w] + rank] = j * 1024 + tid;
  }
  if (tid < 32) {
    const int lo = tid * 256, hi = lo + 256;
    int bl = -1, bE = 0, bLo = 0, bHi = 0;
#pragma unroll
    for (int e = 0; e < N_EXP; ++e) {
      const int a = off[e] > lo ? off[e] : lo;
      const int b = off[e + 1] < hi ? off[e + 1] : hi;
      if (b - a > bl) { bl = b - a; bE = e; bLo = a - lo; bHi = b - lo; }
    }
    sE[tid] = bE; estar[tid] = bE; mlo[tid] = bLo; mhi[tid] = bHi;
  }
  __syncthreads();
  if (tid < N_EXP) {
    int cnt = 0;
    for (int t = 0; t < 32; ++t) {
      if (sE[t] == tid) continue;
      const int lo = t * 256, hi = lo + 256;
      const int a = off[tid] > lo ? off[tid] : lo;
      const int b = off[tid + 1] < hi ? off[tid + 1] : hi;
      if (b > a) cnt += b - a;
    }
    sCnt[tid] = cnt;
  }
  __syncthreads();
  if (tid == 0) {
    int base = 0, ntile = 0;
    for (int e = 0; e < N_EXP; ++e) {
      sBase[e] = base;
      const int pt = (sCnt[e] + 127) >> 7;
      for (int k = 0; k < pt; ++k) rtile[ntile++] = e;
      base += pt << 7;
    }
    *rtc = ntile;
  }
  __syncthreads();
  if (tid < N_EXP && sCnt[tid] > 0) {
    int ptr = sBase[tid], firstp = -1;
    for (int t = 0; t < 32; ++t) {
      if (sE[t] == tid) continue;
      const int lo = t * 256, hi = lo + 256;
      const int a = off[tid] > lo ? off[tid] : lo;
      const int b = off[tid + 1] < hi ? off[tid + 1] : hi;
      for (int p = a; p < b; ++p) { if (firstp < 0) firstp = p; rpos[ptr++] = p; }
    }
    const int end = sBase[tid] + (((sCnt[tid] + 127) >> 7) << 7);
    for (; ptr < end; ++ptr) rpos[ptr] = (int)((unsigned)firstp | FLAGBIT);
  }
}

// ---- main grouped GEMM: 256x256, BK=64, 8-phase; A via GLL (bf16 xb),
//      B reg-staged f32->bf16 (load p0/p4, cvt p3/p7 after vmcnt(0), write p4/p0).
//      Liveness proof: buf.B read only in q0-phase; buf.A last read in q3-phase;
//      all stages target the OTHER buffer and land post-free, pre-barrier. ----
template<int Q, bool FULL, bool VMC0>
__device__ __forceinline__ void gphase(const char* LP, char* LW,
    __attribute__((address_space(3))) char* LDS3,
    int rdBase, int aRowOff, int bRowOff, int ch0, int ch1,
    bf16x8 (&bfr)[8], f32x4 (&acc)[8][4], f32x4 (&bv)[8], uint4 (&bw)[4],
    const unsigned short* a00, const unsigned short* a01,
    const unsigned short* a10, const unsigned short* a11,
    const float* bF0, const float* bF1, int kkB,
    int sl0, int sl1, int wO0, int wO1, int wO2, int wO3)
{
  const int dstO = rdBase ^ 65536;
  if constexpr (FULL) {
    // previous-cvt B tile -> other buffer's B region (free since its q0)
    *reinterpret_cast<uint4*>(LW + dstO + wO0) = bw[0];
    *reinterpret_cast<uint4*>(LW + dstO + wO1) = bw[1];
    *reinterpret_cast<uint4*>(LW + dstO + wO2) = bw[2];
    *reinterpret_cast<uint4*>(LW + dstO + wO3) = bw[3];
#pragma unroll
    for (int nf = 0; nf < 4; ++nf) {
      bfr[nf * 2 + 0] = *reinterpret_cast<const bf16x8*>(LP + rdBase + 32768 + bRowOff + nf * 2048 + ch0);
      bfr[nf * 2 + 1] = *reinterpret_cast<const bf16x8*>(LP + rdBase + 32768 + bRowOff + nf * 2048 + ch1);
    }
  }
  bf16x8 af[2][2];
#pragma unroll
  for (int m = 0; m < 2; ++m) {
    af[m][0] = *reinterpret_cast<const bf16x8*>(LP + rdBase + aRowOff + (2 * Q + m) * 2048 + ch0);
    af[m][1] = *reinterpret_cast<const bf16x8*>(LP + rdBase + aRowOff + (2 * Q + m) * 2048 + ch1);
  }
  if constexpr (FULL) {
    bv[0] = *reinterpret_cast<const f32x4*>(bF0 + kkB);
    bv[1] = *reinterpret_cast<const f32x4*>(bF0 + kkB + 4);
    bv[2] = *reinterpret_cast<const f32x4*>(bF0 + kkB + 8);
    bv[3] = *reinterpret_cast<const f32x4*>(bF0 + kkB + 12);
    bv[4] = *reinterpret_cast<const f32x4*>(bF1 + kkB);
    bv[5] = *reinterpret_cast<const f32x4*>(bF1 + kkB + 4);
    bv[6] = *reinterpret_cast<const f32x4*>(bF1 + kkB + 8);
    bv[7] = *reinterpret_cast<const f32x4*>(bF1 + kkB + 12);
    GLL(a00, LDS3 + dstO + 0 + sl0);
    GLL(a01, LDS3 + dstO + 0 + sl1);
    GLL(a10, LDS3 + dstO + 16384 + sl0);
    GLL(a11, LDS3 + dstO + 16384 + sl1);
  }
  __builtin_amdgcn_sched_barrier(0);
  __builtin_amdgcn_s_barrier();
  __builtin_amdgcn_sched_barrier(0);
  __builtin_amdgcn_s_setprio(1);
#pragma unroll
  for (int ks = 0; ks < 2; ++ks)
#pragma unroll
    for (int m = 0; m < 2; ++m)
#pragma unroll
      for (int nf = 0; nf < 4; ++nf)
        acc[2 * Q + m][nf] = __builtin_amdgcn_mfma_f32_16x16x32_bf16(af[m][ks], bfr[nf * 2 + ks], acc[2 * Q + m][nf], 0, 0, 0);
  __builtin_amdgcn_s_setprio(0);
  if constexpr (VMC0) {
    asm volatile("s_waitcnt vmcnt(0)" ::: "memory");  // retire B loads + A GLLs (3-phase lead)
    bw[0] = pk16(bv[0], bv[1]); bw[1] = pk16(bv[2], bv[3]);
    bw[2] = pk16(bv[4], bv[5]); bw[3] = pk16(bv[6], bv[7]);
  }
  if constexpr (FULL) {
    asm volatile("s_waitcnt lgkmcnt(0)" ::: "memory"); // B ds_writes visible past barrier
  }
  __builtin_amdgcn_sched_barrier(0);
  __builtin_amdgcn_s_barrier();
  __builtin_amdgcn_sched_barrier(0);
}

__global__ __launch_bounds__(512, 2) void k_gemm(const unsigned short* __restrict__ xb,
    const float* __restrict__ we, const int* __restrict__ tlist,
    const int* __restrict__ estar, const int* __restrict__ mlo, const int* __restrict__ mhi,
    float* __restrict__ out)
{
  __shared__ short lds[65536];  // buf0 @0, buf1 @65536; per buf: A 32KB, B 32KB
  const int bid = blockIdx.x;
  const int mt = (bid & 7) * 4 + ((bid >> 3) & 3);  // XCD-locality map
  const int nt = bid >> 5;
  const int m0 = mt * 256, f0 = nt * 256;
  const int e = estar[mt], mLo = mlo[mt], mHi = mhi[mt];
  const int tid = threadIdx.x;
  const int l = tid & 63, wv = tid >> 6;
  const int wm = wv >> 2, wn = wv & 3;
  const int l16 = l & 15, g = l >> 4;
  const char* LP = (const char*)lds;
  char* LW = (char*)lds;
  auto* LDS3 = (__attribute__((address_space(3))) char*)lds;

  const int sw = l16 & 7;
  const int ch0 = ((0 + g) ^ sw) << 4;
  const int ch1 = ((4 + g) ^ sw) << 4;
  const int aRowOff = (wm * 128 + l16) * 128;
  const int bRowOff = (wn * 64 + l16) * 128;

  // A staging (GLL, pre-swizzled source)
  const int csrc = ((l & 7) ^ ((l >> 3) & 7)) * 8;
  const int srow = l >> 3;
  const unsigned short *a00, *a01, *a10, *a11;
  {
    const int t00 = tlist[m0 + 0 * 128 + (wv * 2 + 0) * 8 + srow];
    const int t01 = tlist[m0 + 0 * 128 + (wv * 2 + 1) * 8 + srow];
    const int t10 = tlist[m0 + 1 * 128 + (wv * 2 + 0) * 8 + srow];
    const int t11 = tlist[m0 + 1 * 128 + (wv * 2 + 1) * 8 + srow];
    a00 = xb + (size_t)t00 * H_DIM + csrc;
    a01 = xb + (size_t)t01 * H_DIM + csrc;
    a10 = xb + (size_t)t10 * H_DIM + csrc;
    a11 = xb + (size_t)t11 * H_DIM + csrc;
  }
  const int sl0 = wv * 2048, sl1 = wv * 2048 + 1024;

  // B staging (f32 reg-stage): thread -> row rB, 2 chunks (cols cB..cB+15 f32) per half
  const int rB = tid >> 2;
  const int cB = (tid & 3) * 16;
  const float* bF0 = we + (size_t)e * H_DIM * H_DIM + (size_t)(f0 + rB) * H_DIM + cB;
  const float* bF1 = bF0 + (size_t)128 * H_DIM;
  const int s0c = 2 * (tid & 3), rk = rB & 7;
  const int wO0 = 32768 + rB * 128 + ((s0c ^ rk) << 4);
  const int wO1 = 32768 + rB * 128 + (((s0c + 1) ^ rk) << 4);
  const int wO2 = wO0 + 16384;
  const int wO3 = wO1 + 16384;

  f32x4 acc[8][4];
#pragma unroll
  for (int mf = 0; mf < 8; ++mf)
#pragma unroll
    for (int nf = 0; nf < 4; ++nf) acc[mf][nf] = (f32x4){0.f, 0.f, 0.f, 0.f};
  bf16x8 bfr[8];
  f32x4 bv[8];
  uint4 bw[4];

  // ---- prologue: B(t0) -> buf0.B; then B(t1) regs + A(t0) GLL -> buf0.A ----
  bv[0] = *reinterpret_cast<const f32x4*>(bF0);      bv[1] = *reinterpret_cast<const f32x4*>(bF0 + 4);
  bv[2] = *reinterpret_cast<const f32x4*>(bF0 + 8);  bv[3] = *reinterpret_cast<const f32x4*>(bF0 + 12);
  bv[4] = *reinterpret_cast<const f32x4*>(bF1);      bv[5] = *reinterpret_cast<const f32x4*>(bF1 + 4);
  bv[6] = *reinterpret_cast<const f32x4*>(bF1 + 8);  bv[7] = *reinterpret_cast<const f32x4*>(bF1 + 12);
  bw[0] = pk16(bv[0], bv[1]); bw[1] = pk16(bv[2], bv[3]);
  bw[2] = pk16(bv[4], bv[5]); bw[3] = pk16(bv[6], bv[7]);
  *reinterpret_cast<uint4*>(LW + wO0) = bw[0];
  *reinterpret_cast<uint4*>(LW + wO1) = bw[1];
  *reinterpret_cast<uint4*>(LW + wO2) = bw[2];
  *reinterpret_cast<uint4*>(LW + wO3) = bw[3];
  bv[0] = *reinterpret_cast<const f32x4*>(bF0 + 64);      bv[1] = *reinterpret_cast<const f32x4*>(bF0 + 68);
  bv[2] = *reinterpret_cast<const f32x4*>(bF0 + 72);      bv[3] = *reinterpret_cast<const f32x4*>(bF0 + 76);
  bv[4] = *reinterpret_cast<const f32x4*>(bF1 + 64);      bv[5] = *reinterpret_cast<const f32x4*>(bF1 + 68);
  bv[6] = *reinterpret_cast<const f32x4*>(bF1 + 72);      bv[7] = *reinterpret_cast<const f32x4*>(bF1 + 76);
  GLL(a00, LDS3 + 0 + sl0);
  GLL(a01, LDS3 + 0 + sl1);
  GLL(a10, LDS3 + 16384 + sl0);
  GLL(a11, LDS3 + 16384 + sl1);
  bw[0] = pk16(bv[0], bv[1]); bw[1] = pk16(bv[2], bv[3]);   // B(t1), written at first p0
  bw[2] = pk16(bv[4], bv[5]); bw[3] = pk16(bv[6], bv[7]);
  asm volatile("s_waitcnt vmcnt(0)" ::: "memory");
  asm volatile("s_waitcnt lgkmcnt(0)" ::: "memory");
  __builtin_amdgcn_sched_barrier(0);
  __builtin_amdgcn_s_barrier();
  __builtin_amdgcn_sched_barrier(0);

  for (int i = 0; i < 16; ++i) {
    const int kk1 = (2 * i + 1) << 6;
    const int kk2 = ((2 * i + 2) << 6) & (H_DIM - 1);
    const int kk3 = ((2 * i + 3) << 6) & (H_DIM - 1);
    gphase<0, true , false>(LP, LW, LDS3, 0, aRowOff, bRowOff, ch0, ch1, bfr, acc, bv, bw,
        a00 + kk1, a01 + kk1, a10 + kk1, a11 + kk1, bF0, bF1, kk2, sl0, sl1, wO0, wO1, wO2, wO3);
    gphase<1, false, false>(LP, LW, LDS3, 0, aRowOff, bRowOff, ch0, ch1, bfr, acc, bv, bw,
        a00, a01, a10, a11, bF0, bF1, 0, sl0, sl1, wO0, wO1, wO2, wO3);
    gphase<2, false, false>(LP, LW, LDS3, 0, aRowOff, bRowOff, ch0, ch1, bfr, acc, bv, bw,
        a00, a01, a10, a11, bF0, bF1, 0, sl0, sl1, wO0, wO1, wO2, wO3);
    gphase<3, false, true >(LP, LW, LDS3, 0, aRowOff, bRowOff, ch0, ch1, bfr, acc, bv, bw,
        a00, a01, a10, a11, bF0, bF1, 0, sl0, sl1, wO0, wO1, wO2, wO3);
    gphase<0, true , false>(LP, LW, LDS3, 65536, aRowOff, bRowOff, ch0, ch1, bfr, acc, bv, bw,
        a00 + kk2, a01 + kk2, a10 + kk2, a11 + kk2, bF0, bF1, kk3, sl0, sl1, wO0, wO1, wO2, wO3);
    gphase<1, false, false>(LP, LW, LDS3, 65536, aRowOff, bRowOff, ch0, ch1, bfr, acc, bv, bw,
        a00, a01, a10, a11, bF0, bF1, 0, sl0, sl1, wO0, wO1, wO2, wO3);
    gphase<2, false, false>(LP, LW, LDS3, 65536, aRowOff, bRowOff, ch0, ch1, bfr, acc, bv, bw,
        a00, a01, a10, a11, bF0, bF1, 0, sl0, sl1, wO0, wO1, wO2, wO3);
    gphase<3, false, true >(LP, LW, LDS3, 65536, aRowOff, bRowOff, ch0, ch1, bfr, acc, bv, bw,
        a00, a01, a10, a11, bF0, bF1, 0, sl0, sl1, wO0, wO1, wO2, wO3);
  }

  // epilogue: rows in [mLo,mHi) own results; others zeroed (base for repair atomicAdd)
#pragma unroll
  for (int mf = 0; mf < 8; ++mf) {
#pragma unroll
    for (int r = 0; r < 4; ++r) {
      const int row = wm * 128 + mf * 16 + g * 4 + r;
      const int t = tlist[m0 + row];
      const bool own = (row >= mLo) && (row < mHi);
      float* op = out + (size_t)t * H_DIM + f0 + wn * 64 + l16;
#pragma unroll
      for (int nf = 0; nf < 4; ++nf) op[nf * 16] = own ? acc[mf][nf][r] : 0.f;
    }
  }
}

// ---- repair: minority rows, split-K(4), B reg-staged f32->bf16, atomicAdd onto zeros ----
__global__ __launch_bounds__(256, 2) void k_repair(const unsigned short* __restrict__ xb,
    const float* __restrict__ we, const int* __restrict__ tlist,
    const int* __restrict__ rpos, const int* __restrict__ rtile, const int* __restrict__ rtc,
    float* __restrict__ out)
{
  const int bx = blockIdx.x;
  if (bx >= *rtc) return;
  __shared__ short lds[24576];  // A 16KB @0 (128x128B), B 32KB @16384 (256x128B)
  const int f0 = blockIdx.y * 256, kc = blockIdx.z;
  const int e = rtile[bx];
  const int tid = threadIdx.x, l = tid & 63, wv = tid >> 6;
  const int wm = wv >> 1, wn = wv & 1;
  const int l16 = l & 15, g = l >> 4;
  const char* LP = (const char*)lds;
  char* LW = (char*)lds;
  auto* LDS3 = (__attribute__((address_space(3))) char*)lds;
  const int sw = l16 & 7;
  const int ch0 = ((0 + g) ^ sw) << 4, ch1 = ((4 + g) ^ sw) << 4;
  const int csrc = ((l & 7) ^ ((l >> 3) & 7)) * 8;
  const int srow = l >> 3;

  const unsigned short* aS[4];
#pragma unroll
  for (int j = 0; j < 4; ++j) {
    const int ent = rpos[bx * 128 + (wv * 4 + j) * 8 + srow];
    const int tok = tlist[ent & 0x7fffffff];
    aS[j] = xb + (size_t)tok * H_DIM + csrc;
  }
  // B f32 staging: thread -> base row rR (0..31), slot sR; covers rows rR+32j
  const int rR = tid >> 3, sR = tid & 7;
  const int swO = 16384 + rR * 128 + ((sR ^ (rR & 7)) << 4);
  const float* bFr = we + (size_t)e * H_DIM * H_DIM + (size_t)(f0 + rR) * H_DIM + sR * 8;

  f32x4 acc[4][8];
#pragma unroll
  for (int mf = 0; mf < 4; ++mf)
#pragma unroll
    for (int nf = 0; nf < 8; ++nf) acc[mf][nf] = (f32x4){0.f, 0.f, 0.f, 0.f};

  for (int it = 0; it < 8; ++it) {
    const int kk = kc * 512 + it * 64;
    __syncthreads();
#pragma unroll
    for (int j = 0; j < 4; ++j) GLL(aS[j] + kk, LDS3 + (wv * 4 + j) * 1024);
    f32x4 bv[16];
#pragma unroll
    for (int j = 0; j < 8; ++j) {
      const float* s = bFr + (size_t)(32 * j) * H_DIM + kk;
      bv[2 * j]     = *reinterpret_cast<const f32x4*>(s);
      bv[2 * j + 1] = *reinterpret_cast<const f32x4*>(s + 4);
    }
#pragma unroll
    for (int j = 0; j < 8; ++j)
      *reinterpret_cast<uint4*>(LW + swO + j * 4096) = pk16(bv[2 * j], bv[2 * j + 1]);
    __syncthreads();
    bf16x8 af[4][2];
#pragma unroll
    for (int mf = 0; mf < 4; ++mf) {
      af[mf][0] = *reinterpret_cast<const bf16x8*>(LP + (wm * 64 + mf * 16 + l16) * 128 + ch0);
      af[mf][1] = *reinterpret_cast<const bf16x8*>(LP + (wm * 64 + mf * 16 + l16) * 128 + ch1);
    }
#pragma unroll
    for (int nf = 0; nf < 8; ++nf) {
      const bf16x8 b0 = *reinterpret_cast<const bf16x8*>(LP + 16384 + (wn * 128 + nf * 16 + l16) * 128 + ch0);
      const bf16x8 b1 = *reinterpret_cast<const bf16x8*>(LP + 16384 + (wn * 128 + nf * 16 + l16) * 128 + ch1);
#pragma unroll
      for (int mf = 0; mf < 4; ++mf) {
        acc[mf][nf] = __builtin_amdgcn_mfma_f32_16x16x32_bf16(af[mf][0], b0, acc[mf][nf], 0, 0, 0);
        acc[mf][nf] = __builtin_amdgcn_mfma_f32_16x16x32_bf16(af[mf][1], b1, acc[mf][nf], 0, 0, 0);
      }
    }
  }
#pragma unroll
  for (int mf = 0; mf < 4; ++mf) {
#pragma unroll
    for (int r = 0; r < 4; ++r) {
      const int row = wm * 64 + mf * 16 + g * 4 + r;
      const int ent = rpos[bx * 128 + row];
      if (!((unsigned)ent & FLAGBIT)) {
        const int tok = tlist[ent];
        float* op = out + (size_t)tok * H_DIM + f0 + wn * 128 + l16;
#pragma unroll
        for (int nf = 0; nf < 8; ++nf) atomicAdd(op + nf * 16, acc[mf][nf][r]);
      }
    }
  }
}

extern "C" void kernel_launch(void* const* d_in, const int* in_sizes, int n_in,
                              void* d_out, int out_size, void* d_ws, size_t ws_size,
                              hipStream_t stream) {
  const float* x  = (const float*)d_in[0];
  const float* wr = (const float*)d_in[1];
  const float* we = (const float*)d_in[2];
  float* out = (float*)d_out;

  char* p = (char*)d_ws;
  unsigned short* xb = (unsigned short*)p; p += (size_t)T_TOK * H_DIM * 2;  // 32 MB
  int* idx    = (int*)p; p += T_TOK * 4;
  int* tlist  = (int*)p; p += T_TOK * 4;
  int* rpos   = (int*)p; p += T_TOK * 4;
  int* estar  = (int*)p; p += 32 * 4;
  int* mlo    = (int*)p; p += 32 * 4;
  int* mhi    = (int*)p; p += 32 * 4;
  int* rtile  = (int*)p; p += 64 * 4;
  int* rtc    = (int*)p; p += 64;

  k_router<<<512, 256, 0, stream>>>(x, wr, xb, idx);
  k_sort<<<1, 1024, 0, stream>>>(idx, tlist, estar, mlo, mhi, rpos, rtile, rtc);
  k_gemm<<<256, 512, 0, stream>>>(xb, we, tlist, estar, mlo, mhi, out);
  k_repair<<<dim3(64, 8, 4), 256, 0, stream>>>(xb, we, tlist, rpos, rtile, rtc, out);
}

// Round 11
// 199.640 us; speedup vs baseline: 1.2652x; 1.2652x over previous
//
#include <hip/hip_runtime.h>
#include <hip/hip_bf16.h>
#include <cstdint>

#define T_TOK 8192
#define H_DIM 2048
#define N_EXP 8
#define FLAGBIT 0x80000000u

typedef __attribute__((ext_vector_type(4))) float f32x4;
typedef __attribute__((ext_vector_type(8))) short bf16x8;

__device__ __forceinline__ unsigned short f2bf(float f) {
  unsigned int u = __builtin_bit_cast(unsigned int, f);
  u += 0x7fffu + ((u >> 16) & 1u);  // RNE
  return (unsigned short)(u >> 16);
}

#define GLL(SRC, DST) __builtin_amdgcn_global_load_lds( \
    (const __attribute__((address_space(1))) void*)(SRC), \
    (__attribute__((address_space(3))) void*)(DST), 16, 0, 0)

// ---- fused pre: blocks <4096 = W f32->bf16 streaming (4 sweeps, 8 blk/CU-ish);
//      blocks >=4096 = router 1 tok/wave (max TLP, atomic-free) + x bf16 cast ----
__global__ __launch_bounds__(256, 4) void k_pre(const float* __restrict__ x,
    const float* __restrict__ wr, const float* __restrict__ we,
    unsigned short* __restrict__ xb, unsigned short* __restrict__ wb,
    int* __restrict__ idx)
{
  const int bid = blockIdx.x;
  if (bid < 4096) {  // conv: 4096 blocks x 256 thr x 4 sweeps x 8 f32
    const size_t tix = ((size_t)bid * 256 + threadIdx.x) * 8;
    const size_t stride = (size_t)4096 * 256 * 8;  // 8,388,608 elems
#pragma unroll
    for (int it = 0; it < 4; ++it) {
      const f32x4 a = *reinterpret_cast<const f32x4*>(we + tix + (size_t)it * stride);
      const f32x4 b = *reinterpret_cast<const f32x4*>(we + tix + (size_t)it * stride + 4);
      union { unsigned short h[8]; uint4 u; } r;
#pragma unroll
      for (int q = 0; q < 4; ++q) { r.h[q] = f2bf(a[q]); r.h[4 + q] = f2bf(b[q]); }
      *reinterpret_cast<uint4*>(wb + tix + (size_t)it * stride) = r.u;
    }
    return;
  }
  // router: 1 token/wave, 2048 blocks -> 8 blocks/CU of TLP
  const int wv = threadIdx.x >> 6, lane = threadIdx.x & 63;
  const int t = (bid - 4096) * 4 + wv;
  const float* xp = x + (size_t)t * H_DIM;
  float acc[N_EXP];
#pragma unroll
  for (int e = 0; e < N_EXP; ++e) acc[e] = 0.f;
#pragma unroll
  for (int c = 0; c < H_DIM / 256; ++c) {
    const int h = c * 256 + lane * 4;
    const float4 xv = *reinterpret_cast<const float4*>(xp + h);
    ushort4 bv;
    bv.x = f2bf(xv.x); bv.y = f2bf(xv.y); bv.z = f2bf(xv.z); bv.w = f2bf(xv.w);
    *reinterpret_cast<ushort4*>(xb + (size_t)t * H_DIM + h) = bv;
#pragma unroll
    for (int e = 0; e < N_EXP; ++e) {
      const float4 wv4 = *reinterpret_cast<const float4*>(wr + e * H_DIM + h);
      acc[e] = fmaf(xv.x, wv4.x, acc[e]);
      acc[e] = fmaf(xv.y, wv4.y, acc[e]);
      acc[e] = fmaf(xv.z, wv4.z, acc[e]);
      acc[e] = fmaf(xv.w, wv4.w, acc[e]);
    }
  }
#pragma unroll
  for (int off = 32; off >= 1; off >>= 1)
#pragma unroll
    for (int e = 0; e < N_EXP; ++e) acc[e] += __shfl_xor(acc[e], off, 64);
  if (lane == 0) {
    float best = acc[0]; int be = 0;
#pragma unroll
    for (int e = 1; e < N_EXP; ++e) if (acc[e] > best) { best = acc[e]; be = e; }
    idx[t] = be;
  }
}

// ---- fused sort: hist + scan + stable place + maps, one block of 1024 ----
__global__ __launch_bounds__(1024) void k_sort(const int* __restrict__ idx,
    int* __restrict__ tlist, int* __restrict__ estar, int* __restrict__ mlo,
    int* __restrict__ mhi, int* __restrict__ rpos, int* __restrict__ rtile,
    int* __restrict__ rtc)
{
  __shared__ int wc[N_EXP][128];
  __shared__ int wbase[N_EXP][128];
  __shared__ int sTot[N_EXP];
  __shared__ int off[N_EXP + 1];
  __shared__ int sE[32], sCnt[N_EXP], sBase[N_EXP];
  const int tid = threadIdx.x, w = tid >> 6, l = tid & 63;
  int myE[8];
#pragma unroll
  for (int j = 0; j < 8; ++j) {
    myE[j] = idx[j * 1024 + tid];
#pragma unroll
    for (int e = 0; e < N_EXP; ++e) {
      const unsigned long long bm = __ballot(myE[j] == e);
      if (l == e) wc[e][j * 16 + w] = __popcll(bm);
    }
  }
  __syncthreads();
  if (tid < N_EXP) {
    int s = 0;
    for (int k = 0; k < 128; ++k) { wbase[tid][k] = s; s += wc[tid][k]; }
    sTot[tid] = s;
  }
  __syncthreads();
  if (tid == 0) {
    off[0] = 0;
    for (int e = 0; e < N_EXP; ++e) off[e + 1] = off[e] + sTot[e];
  }
  __syncthreads();
#pragma unroll
  for (int j = 0; j < 8; ++j) {
    int rank = 0;
#pragma unroll
    for (int e = 0; e < N_EXP; ++e) {
      const unsigned long long bm = __ballot(myE[j] == e);
      if (myE[j] == e) rank = __popcll(bm & ((1ull << l) - 1ull));
    }
    tlist[off[myE[j]] + wbase[myE[j]][j * 16 + w] + rank] = j * 1024 + tid;
  }
  if (tid < 32) {
    const int lo = tid * 256, hi = lo + 256;
    int bl = -1, bE = 0, bLo = 0, bHi = 0;
#pragma unroll
    for (int e = 0; e < N_EXP; ++e) {
      const int a = off[e] > lo ? off[e] : lo;
      const int b = off[e + 1] < hi ? off[e + 1] : hi;
      if (b - a > bl) { bl = b - a; bE = e; bLo = a - lo; bHi = b - lo; }
    }
    sE[tid] = bE; estar[tid] = bE; mlo[tid] = bLo; mhi[tid] = bHi;
  }
  __syncthreads();
  if (tid < N_EXP) {
    int cnt = 0;
    for (int t = 0; t < 32; ++t) {
      if (sE[t] == tid) continue;
      const int lo = t * 256, hi = lo + 256;
      const int a = off[tid] > lo ? off[tid] : lo;
      const int b = off[tid + 1] < hi ? off[tid + 1] : hi;
      if (b > a) cnt += b - a;
    }
    sCnt[tid] = cnt;
  }
  __syncthreads();
  if (tid == 0) {
    int base = 0, ntile = 0;
    for (int e = 0; e < N_EXP; ++e) {
      sBase[e] = base;
      const int pt = (sCnt[e] + 127) >> 7;
      for (int k = 0; k < pt; ++k) rtile[ntile++] = e;
      base += pt << 7;
    }
    *rtc = ntile;
  }
  __syncthreads();
  if (tid < N_EXP && sCnt[tid] > 0) {
    int ptr = sBase[tid], firstp = -1;
    for (int t = 0; t < 32; ++t) {
      if (sE[t] == tid) continue;
      const int lo = t * 256, hi = lo + 256;
      const int a = off[tid] > lo ? off[tid] : lo;
      const int b = off[tid + 1] < hi ? off[tid + 1] : hi;
      for (int p = a; p < b; ++p) { if (firstp < 0) firstp = p; rpos[ptr++] = p; }
    }
    const int end = sBase[tid] + (((sCnt[tid] + 127) >> 7) << 7);
    for (; ptr < end; ++ptr) rpos[ptr] = (int)((unsigned)firstp | FLAGBIT);
  }
}

// ---- r9 8-phase gphase (bf16 wb, GLL both operands, counted vmcnt) ----
template<int Q, bool LOADB, bool VMC>
__device__ __forceinline__ void gphase(const char* LP,
    __attribute__((address_space(3))) char* LDS3,
    int rdBase, int aRowOff, int bRowOff, int ch0, int ch1,
    bf16x8 (&bfr)[8], f32x4 (&acc)[8][4],
    const unsigned short* s0, const unsigned short* s1, int d0, int d1)
{
  if constexpr (LOADB) {
#pragma unroll
    for (int nf = 0; nf < 4; ++nf) {
      bfr[nf * 2 + 0] = *reinterpret_cast<const bf16x8*>(LP + rdBase + 32768 + bRowOff + nf * 2048 + ch0);
      bfr[nf * 2 + 1] = *reinterpret_cast<const bf16x8*>(LP + rdBase + 32768 + bRowOff + nf * 2048 + ch1);
    }
  }
  bf16x8 af[2][2];
#pragma unroll
  for (int m = 0; m < 2; ++m) {
    af[m][0] = *reinterpret_cast<const bf16x8*>(LP + rdBase + aRowOff + (2 * Q + m) * 2048 + ch0);
    af[m][1] = *reinterpret_cast<const bf16x8*>(LP + rdBase + aRowOff + (2 * Q + m) * 2048 + ch1);
  }
  GLL(s0, LDS3 + d0);
  GLL(s1, LDS3 + d1);
  __builtin_amdgcn_sched_barrier(0);
  __builtin_amdgcn_s_barrier();
  __builtin_amdgcn_sched_barrier(0);
  __builtin_amdgcn_s_setprio(1);
#pragma unroll
  for (int ks = 0; ks < 2; ++ks)
#pragma unroll
    for (int m = 0; m < 2; ++m)
#pragma unroll
      for (int nf = 0; nf < 4; ++nf)
        acc[2 * Q + m][nf] = __builtin_amdgcn_mfma_f32_16x16x32_bf16(af[m][ks], bfr[nf * 2 + ks], acc[2 * Q + m][nf], 0, 0, 0);
  __builtin_amdgcn_s_setprio(0);
  if constexpr (VMC) asm volatile("s_waitcnt vmcnt(4)" ::: "memory");
  __builtin_amdgcn_sched_barrier(0);
  __builtin_amdgcn_s_barrier();
  __builtin_amdgcn_sched_barrier(0);
}

// ---- merged: blocks <256 = main 256x256 grouped GEMM (skip minority rows);
//      blocks 256..767 = repair (full-K, plain stores, owns minority cells) ----
__global__ __launch_bounds__(512, 2) void k_gemm(const unsigned short* __restrict__ xb,
    const unsigned short* __restrict__ wb, const int* __restrict__ tlist,
    const int* __restrict__ estar, const int* __restrict__ mlo, const int* __restrict__ mhi,
    const int* __restrict__ rpos, const int* __restrict__ rtile, const int* __restrict__ rtc,
    float* __restrict__ out)
{
  __shared__ short lds[65536];  // 128 KiB
  const int bid = blockIdx.x;
  const int tid = threadIdx.x;
  const int l = tid & 63, wv = tid >> 6;
  const int l16 = l & 15, g = l >> 4;
  const char* LP = (const char*)lds;
  auto* LDS3 = (__attribute__((address_space(3))) char*)lds;
  const int sw = l16 & 7;
  const int ch0 = ((0 + g) ^ sw) << 4;
  const int ch1 = ((4 + g) ^ sw) << 4;
  const int csrc = ((l & 7) ^ ((l >> 3) & 7)) * 8;
  const int srow = l >> 3;

  if (bid < 256) {
    // ---------------- main GEMM (r9 verbatim, epilogue skips !own) ----------------
    const int mt = (bid & 7) * 4 + ((bid >> 3) & 3);  // XCD-locality map
    const int nt = bid >> 5;
    const int m0 = mt * 256, f0 = nt * 256;
    const int e = estar[mt], mLo = mlo[mt], mHi = mhi[mt];
    const int wm = wv >> 2, wn = wv & 3;
    const int aRowOff = (wm * 128 + l16) * 128;
    const int bRowOff = (wn * 64 + l16) * 128;

    const unsigned short* aP[2][2];
    const unsigned short* bP[2][2];
    const unsigned short* wpan = wb + (size_t)e * H_DIM * H_DIM;
#pragma unroll
    for (int h = 0; h < 2; ++h)
#pragma unroll
      for (int j = 0; j < 2; ++j) {
        const int tok = tlist[m0 + h * 128 + (wv * 2 + j) * 8 + srow];
        aP[h][j] = xb + (size_t)tok * H_DIM + csrc;
        bP[h][j] = wpan + (size_t)(f0 + h * 128 + (wv * 2 + j) * 8 + srow) * H_DIM + csrc;
      }
    const int sl0 = wv * 2048, sl1 = wv * 2048 + 1024;

    f32x4 acc[8][4];
#pragma unroll
    for (int mf = 0; mf < 8; ++mf)
#pragma unroll
      for (int nf = 0; nf < 4; ++nf) acc[mf][nf] = (f32x4){0.f, 0.f, 0.f, 0.f};
    bf16x8 bfr[8];

    GLL(aP[0][0], LDS3 + 0 + sl0);      GLL(aP[0][1], LDS3 + 0 + sl1);
    GLL(aP[1][0], LDS3 + 16384 + sl0);  GLL(aP[1][1], LDS3 + 16384 + sl1);
    GLL(bP[0][0], LDS3 + 32768 + sl0);  GLL(bP[0][1], LDS3 + 32768 + sl1);
    GLL(bP[1][0], LDS3 + 49152 + sl0);  GLL(bP[1][1], LDS3 + 49152 + sl1);
    GLL(bP[0][0] + 64, LDS3 + 65536 + 32768 + sl0);  GLL(bP[0][1] + 64, LDS3 + 65536 + 32768 + sl1);
    GLL(bP[1][0] + 64, LDS3 + 65536 + 49152 + sl0);  GLL(bP[1][1] + 64, LDS3 + 65536 + 49152 + sl1);
    asm volatile("s_waitcnt vmcnt(4)" ::: "memory");
    __builtin_amdgcn_sched_barrier(0);
    __builtin_amdgcn_s_barrier();
    __builtin_amdgcn_sched_barrier(0);

    for (int i = 0; i < 16; ++i) {
      const int kk1 = ((2 * i + 1) << 6) & (H_DIM - 1);
      const int kk2 = ((2 * i + 2) << 6) & (H_DIM - 1);
      const int kk3 = ((2 * i + 3) << 6) & (H_DIM - 1);
      gphase<0, true , false>(LP, LDS3, 0, aRowOff, bRowOff, ch0, ch1, bfr, acc,
          aP[0][0] + kk1, aP[0][1] + kk1, 65536 + 0 + sl0, 65536 + 0 + sl1);
      gphase<1, false, false>(LP, LDS3, 0, aRowOff, bRowOff, ch0, ch1, bfr, acc,
          aP[1][0] + kk1, aP[1][1] + kk1, 65536 + 16384 + sl0, 65536 + 16384 + sl1);
      gphase<2, false, false>(LP, LDS3, 0, aRowOff, bRowOff, ch0, ch1, bfr, acc,
          bP[0][0] + kk2, bP[0][1] + kk2, 0 + 32768 + sl0, 0 + 32768 + sl1);
      gphase<3, false, true >(LP, LDS3, 0, aRowOff, bRowOff, ch0, ch1, bfr, acc,
          bP[1][0] + kk2, bP[1][1] + kk2, 0 + 49152 + sl0, 0 + 49152 + sl1);
      gphase<0, true , false>(LP, LDS3, 65536, aRowOff, bRowOff, ch0, ch1, bfr, acc,
          aP[0][0] + kk2, aP[0][1] + kk2, 0 + 0 + sl0, 0 + 0 + sl1);
      gphase<1, false, false>(LP, LDS3, 65536, aRowOff, bRowOff, ch0, ch1, bfr, acc,
          aP[1][0] + kk2, aP[1][1] + kk2, 0 + 16384 + sl0, 0 + 16384 + sl1);
      gphase<2, false, false>(LP, LDS3, 65536, aRowOff, bRowOff, ch0, ch1, bfr, acc,
          bP[0][0] + kk3, bP[0][1] + kk3, 65536 + 32768 + sl0, 65536 + 32768 + sl1);
      gphase<3, false, true >(LP, LDS3, 65536, aRowOff, bRowOff, ch0, ch1, bfr, acc,
          bP[1][0] + kk3, bP[1][1] + kk3, 65536 + 49152 + sl0, 65536 + 49152 + sl1);
    }

#pragma unroll
    for (int mf = 0; mf < 8; ++mf) {
#pragma unroll
      for (int r = 0; r < 4; ++r) {
        const int row = wm * 128 + mf * 16 + g * 4 + r;
        if (row >= mLo && row < mHi) {   // minority rows owned by repair blocks
          const int t = tlist[m0 + row];
          float* op = out + (size_t)t * H_DIM + f0 + wn * 64 + l16;
#pragma unroll
          for (int nf = 0; nf < 4; ++nf) op[nf * 16] = acc[mf][nf][r];
        }
      }
    }
    return;
  }

  // ---------------- repair: 128x256 tile, full K, plain stores ----------------
  const int bid2 = bid - 256;
  const int bx = bid2 >> 3;
  if (bx >= *rtc) return;
  const int f0 = (bid2 & 7) * 256;
  const int e = rtile[bx];
  const int wm = wv >> 2, wn = wv & 3;   // 2M x 4N waves, 64x64 out each

  const unsigned short* aS[2];
#pragma unroll
  for (int j = 0; j < 2; ++j) {
    const int ent = rpos[bx * 128 + (wv * 2 + j) * 8 + srow];
    const int tok = tlist[ent & 0x7fffffff];
    aS[j] = xb + (size_t)tok * H_DIM + csrc;
  }
  const unsigned short* bS[4];
#pragma unroll
  for (int j = 0; j < 4; ++j)
    bS[j] = wb + (size_t)e * H_DIM * H_DIM + (size_t)(f0 + (wv * 4 + j) * 8 + srow) * H_DIM + csrc;

  f32x4 acc[4][4];
#pragma unroll
  for (int mf = 0; mf < 4; ++mf)
#pragma unroll
    for (int nf = 0; nf < 4; ++nf) acc[mf][nf] = (f32x4){0.f, 0.f, 0.f, 0.f};

  for (int it = 0; it < 32; ++it) {
    const int kk = it * 64;
    __syncthreads();
#pragma unroll
    for (int j = 0; j < 2; ++j) GLL(aS[j] + kk, LDS3 + (wv * 2 + j) * 1024);
#pragma unroll
    for (int j = 0; j < 4; ++j) GLL(bS[j] + kk, LDS3 + 16384 + (wv * 4 + j) * 1024);
    __syncthreads();
    bf16x8 af[4][2];
#pragma unroll
    for (int mf = 0; mf < 4; ++mf) {
      af[mf][0] = *reinterpret_cast<const bf16x8*>(LP + (wm * 64 + mf * 16 + l16) * 128 + ch0);
      af[mf][1] = *reinterpret_cast<const bf16x8*>(LP + (wm * 64 + mf * 16 + l16) * 128 + ch1);
    }
#pragma unroll
    for (int nf = 0; nf < 4; ++nf) {
      const bf16x8 b0 = *reinterpret_cast<const bf16x8*>(LP + 16384 + (wn * 64 + nf * 16 + l16) * 128 + ch0);
      const bf16x8 b1 = *reinterpret_cast<const bf16x8*>(LP + 16384 + (wn * 64 + nf * 16 + l16) * 128 + ch1);
#pragma unroll
      for (int mf = 0; mf < 4; ++mf) {
        acc[mf][nf] = __builtin_amdgcn_mfma_f32_16x16x32_bf16(af[mf][0], b0, acc[mf][nf], 0, 0, 0);
        acc[mf][nf] = __builtin_amdgcn_mfma_f32_16x16x32_bf16(af[mf][1], b1, acc[mf][nf], 0, 0, 0);
      }
    }
  }
#pragma unroll
  for (int mf = 0; mf < 4; ++mf) {
#pragma unroll
    for (int r = 0; r < 4; ++r) {
      const int row = wm * 64 + mf * 16 + g * 4 + r;
      const int ent = rpos[bx * 128 + row];
      if (!((unsigned)ent & FLAGBIT)) {
        const int tok = tlist[ent];
        float* op = out + (size_t)tok * H_DIM + f0 + wn * 64 + l16;
#pragma unroll
        for (int nf = 0; nf < 4; ++nf) op[nf * 16] = acc[mf][nf][r];
      }
    }
  }
}

extern "C" void kernel_launch(void* const* d_in, const int* in_sizes, int n_in,
                              void* d_out, int out_size, void* d_ws, size_t ws_size,
                              hipStream_t stream) {
  const float* x  = (const float*)d_in[0];
  const float* wr = (const float*)d_in[1];
  const float* we = (const float*)d_in[2];
  float* out = (float*)d_out;

  char* p = (char*)d_ws;
  unsigned short* xb = (unsigned short*)p; p += (size_t)T_TOK * H_DIM * 2;          // 32 MB
  unsigned short* wb = (unsigned short*)p; p += (size_t)N_EXP * H_DIM * H_DIM * 2;  // 64 MB
  int* idx    = (int*)p; p += T_TOK * 4;
  int* tlist  = (int*)p; p += T_TOK * 4;
  int* rpos   = (int*)p; p += T_TOK * 4;
  int* estar  = (int*)p; p += 32 * 4;
  int* mlo    = (int*)p; p += 32 * 4;
  int* mhi    = (int*)p; p += 32 * 4;
  int* rtile  = (int*)p; p += 64 * 4;
  int* rtc    = (int*)p; p += 64;

  k_pre<<<4096 + 2048, 256, 0, stream>>>(x, wr, we, xb, wb, idx);
  k_sort<<<1, 1024, 0, stream>>>(idx, tlist, estar, mlo, mhi, rpos, rtile, rtc);
  k_gemm<<<768, 512, 0, stream>>>(xb, wb, tlist, estar, mlo, mhi, rpos, rtile, rtc, out);
}